// Round 1
// baseline (223.480 us; speedup 1.0000x reference)
//
#include <hip/hip_runtime.h>
#include <stdint.h>

// ---- problem constants ----
#define Bz 8
#define Tz 1024
#define Cz 768
#define Hz 8
#define Dz 96
#define BHz 64            // Bz*Hz
#define Kz 768

typedef __bf16 bf16x8 __attribute__((ext_vector_type(8)));
typedef unsigned short u16x8 __attribute__((ext_vector_type(8)));
typedef float f32x4 __attribute__((ext_vector_type(4)));

__device__ __forceinline__ unsigned short f2bf(float f) {
  union { float f; unsigned int u; } v; v.f = f;
  unsigned int u = v.u;
  return (unsigned short)((u + 0x7fffu + ((u >> 16) & 1u)) >> 16);
}

#if defined(__has_builtin)
#if __has_builtin(__builtin_amdgcn_exp2f)
#define EXP2(x) __builtin_amdgcn_exp2f(x)
#endif
#endif
#ifndef EXP2
#define EXP2(x) __expf((x) * 0.6931471805599453f)
#endif

// async global->LDS, 16B per lane; LDS dest must be wave-uniform base (+lane*16 implicit)
typedef const __attribute__((address_space(1))) void* gas_ptr;
typedef __attribute__((address_space(3))) void* las_ptr;
__device__ __forceinline__ void gl16(const void* g, void* l) {
  __builtin_amdgcn_global_load_lds((gas_ptr)g, (las_ptr)l, 16, 0, 0);
}

// ---- cast x (fp32) -> bf16, 4 elems/thread ----
__global__ __launch_bounds__(256) void cast_f32_bf16(const float* __restrict__ in,
                                                     unsigned short* __restrict__ out) {
  int i = (blockIdx.x * 256 + threadIdx.x) * 4;
  float4 v = *(const float4*)(in + i);
  union { unsigned short s[4]; uint2 u; } o;
  o.s[0] = f2bf(v.x); o.s[1] = f2bf(v.y); o.s[2] = f2bf(v.z); o.s[3] = f2bf(v.w);
  *(uint2*)(out + i) = o.u;
}

// ---- transpose + cast: in[R][Cc] fp32 -> out[Cc][R] bf16 ----
__global__ __launch_bounds__(256) void transpose_cast(const float* __restrict__ in,
                                                      unsigned short* __restrict__ out,
                                                      int R, int Cc) {
  __shared__ unsigned short t[64][72];
  int bx = blockIdx.x * 64;   // col base of in
  int by = blockIdx.y * 64;   // row base of in
  int tid = threadIdx.x;
#pragma unroll
  for (int i = 0; i < 16; i++) {
    int idx = tid + i * 256;
    int r = idx >> 6, c = idx & 63;
    t[c][r] = f2bf(in[(by + r) * Cc + bx + c]);
  }
  __syncthreads();
#pragma unroll
  for (int i = 0; i < 16; i++) {
    int idx = tid + i * 256;
    int r = idx >> 6, c = idx & 63;
    out[(bx + r) * R + by + c] = t[r][c];
  }
}

// ---- 128x128 MFMA bf16 GEMM with global_load_lds staging (m97 structure) ----
// A[M][K] bf16, Bt[N][K] bf16
// MODE 0: epilogue scatters bf16 into qkv: Q,K as [which][64][1024][96];
//         V third written TRANSPOSED as [64][96][1024] so attn's PV reads it
//         directly from global as the MFMA B-operand (no LDS V staging).
// MODE 1: epilogue writes fp32 C[M][768]
template <int MODE>
__global__ __launch_bounds__(256)
void gemm128(const unsigned short* __restrict__ A,
             const unsigned short* __restrict__ Bt,
             unsigned short* __restrict__ obf,
             float* __restrict__ of32) {
  __shared__ unsigned short Asm[128 * 32];  // unpadded: required by global_load_lds lane order
  __shared__ unsigned short Bsm[128 * 32];
  const int tid = threadIdx.x;
  const int wave = tid >> 6, lane = tid & 63;
  const int quad = lane >> 4, l16 = lane & 15;
  const int bm = blockIdx.x, bn = blockIdx.y;
  const int wm = (wave >> 1) * 64, wn = (wave & 1) * 64;

  f32x4 zero = {0.f, 0.f, 0.f, 0.f};
  f32x4 acc[4][4];
#pragma unroll
  for (int i = 0; i < 4; i++)
#pragma unroll
    for (int j = 0; j < 4; j++) acc[i][j] = zero;

  // staging map: wave w issue q covers rows w*32+q*16 .. +15; lane l -> row +(l>>2), k-part (l&3)*8
  const int rr = lane >> 2, c8 = (lane & 3) * 8;
  const unsigned short* Ag0 = A + (size_t)(bm * 128 + wave * 32 + rr) * Kz + c8;
  const unsigned short* Ag1 = Ag0 + 16 * Kz;
  const unsigned short* Bg0 = Bt + (size_t)(bn * 128 + wave * 32 + rr) * Kz + c8;
  const unsigned short* Bg1 = Bg0 + 16 * Kz;
  unsigned short* lA0 = &Asm[wave * 1024];      // elements; bytes = wave*2048
  unsigned short* lA1 = lA0 + 512;
  unsigned short* lB0 = &Bsm[wave * 1024];
  unsigned short* lB1 = lB0 + 512;

  for (int k0 = 0; k0 < Kz; k0 += 32) {
    __syncthreads();                 // WAR: previous frag reads done
    gl16(Ag0 + k0, lA0);
    gl16(Ag1 + k0, lA1);
    gl16(Bg0 + k0, lB0);
    gl16(Bg1 + k0, lB1);
    __syncthreads();                 // drains vmcnt(0) then barrier
    bf16x8 af[4], bfr[4];
#pragma unroll
    for (int mi = 0; mi < 4; mi++)
      af[mi] = *(const bf16x8*)&Asm[(wm + mi * 16 + l16) * 32 + quad * 8];
#pragma unroll
    for (int ni = 0; ni < 4; ni++)
      bfr[ni] = *(const bf16x8*)&Bsm[(wn + ni * 16 + l16) * 32 + quad * 8];
#pragma unroll
    for (int mi = 0; mi < 4; mi++)
#pragma unroll
      for (int ni = 0; ni < 4; ni++)
        acc[mi][ni] = __builtin_amdgcn_mfma_f32_16x16x32_bf16(af[mi], bfr[ni], acc[mi][ni], 0, 0, 0);
  }

#pragma unroll
  for (int mi = 0; mi < 4; mi++) {
    int row = bm * 128 + wm + mi * 16 + quad * 4;
    if (MODE == 0) {
      int b = row >> 10;
      int t = row & 1023;
#pragma unroll
      for (int ni = 0; ni < 4; ni++) {
        int col = bn * 128 + wn + ni * 16 + l16;
        int which = col / 768;        // wave-uniform per fragment (16 | 768)
        int cc = col - which * 768;
        int h = cc / 96;
        int d = cc - h * 96;
        if (which == 2) {
          // V^T layout: [bh][d][t]; r increments t -> 4 contiguous bf16 = one 8B store
          int base = ((2 * 64 + b * 8 + h) * 96 + d) * 1024 + t;
          union { unsigned short s[4]; uint2 u; } o;
#pragma unroll
          for (int r = 0; r < 4; r++) o.s[r] = f2bf(acc[mi][ni][r]);
          *(uint2*)(obf + base) = o.u;
        } else {
          int base = ((which * 64 + b * 8 + h) * 1024 + t) * 96 + d;
#pragma unroll
          for (int r = 0; r < 4; r++) obf[base + r * 96] = f2bf(acc[mi][ni][r]);
        }
      }
    } else {
#pragma unroll
      for (int ni = 0; ni < 4; ni++) {
        int col = bn * 128 + wn + ni * 16 + l16;
#pragma unroll
        for (int r = 0; r < 4; r++) of32[(row + r) * 768 + col] = acc[mi][ni][r];
      }
    }
  }
}

// ---- flash attention v2: 1 block = (b,h) x 128 q-rows; 4 waves x 32 rows; BS=128 ----
// Barrier-free s-loop: K and V^T read straight from global (L2-resident per head),
// P lives in per-wave LDS (same-wave lgkmcnt ordering, no __syncthreads).
__global__ __launch_bounds__(256, 2)
void attn(const unsigned short* __restrict__ qkv, unsigned short* __restrict__ y) {
  const int bh = blockIdx.x;
  const int by = blockIdx.y;
  // balanced pairing: CU holding blocks n and n+256 gets tiles summing to 9 iters
  const int q0 = ((by < 4) ? (7 - by) : (by - 4)) * 128;
  const int tid = threadIdx.x;
  const int wave = tid >> 6, lane = tid & 63;
  const int quad = lane >> 4, l16 = lane & 15;
  const int qw0 = q0 + wave * 32;          // this wave's 32 q-rows (2 m-tiles)
  const int b = bh >> 3, h = bh & 7;

  const unsigned short* Qh = qkv + bh * Tz * Dz;
  const unsigned short* Kh = qkv + (BHz + bh) * Tz * Dz;
  const unsigned short* Vt = qkv + 2 * BHz * Tz * Dz + bh * Dz * Tz;  // [d][t]

  __shared__ unsigned short Psm[4 * 32 * 136];   // per-wave P [32 q][128 s]
  unsigned short* Pw = Psm + wave * 32 * 136;

  bf16x8 aq[2][3];
#pragma unroll
  for (int mi = 0; mi < 2; mi++)
#pragma unroll
    for (int kd = 0; kd < 3; kd++)
      aq[mi][kd] = *(const bf16x8*)(Qh + (qw0 + mi * 16 + l16) * Dz + kd * 32 + quad * 8);

  f32x4 zero = {0.f, 0.f, 0.f, 0.f};
  f32x4 acc_o[2][6];
#pragma unroll
  for (int mi = 0; mi < 2; mi++)
#pragma unroll
    for (int i = 0; i < 6; i++) acc_o[mi][i] = zero;
  const float NEG = -__builtin_inff();
  float mrow[2][4], lrow[2][4];              // mrow raw-score domain; lrow per-LANE partial
#pragma unroll
  for (int mi = 0; mi < 2; mi++)
#pragma unroll
    for (int r = 0; r < 4; r++) { mrow[mi][r] = NEG; lrow[mi][r] = 0.f; }
  const float cs = 0.14724538519872735f;    // (1/sqrt(96)) * log2(e): exp2-domain softmax

  for (int s0 = 0; s0 <= q0; s0 += 128) {
    const int srem = qw0 + 31 - s0;              // >= 31 always; srem%32==31
    const int nlim = min(7, srem >> 4);          // last 16-wide s tile with unmasked cols
    const int klim = min(3, srem >> 5);          // last 32-wide PV k chunk

    // ---- S = Q K^T (both m-tiles share K fragments) ----
    f32x4 sacc[2][8];
#pragma unroll
    for (int ni = 0; ni < 8; ni++) {
      if (ni <= nlim) {
        sacc[0][ni] = zero; sacc[1][ni] = zero;
#pragma unroll
        for (int kd = 0; kd < 3; kd++) {
          bf16x8 bk = *(const bf16x8*)(Kh + (s0 + ni * 16 + l16) * Dz + kd * 32 + quad * 8);
          sacc[0][ni] = __builtin_amdgcn_mfma_f32_16x16x32_bf16(aq[0][kd], bk, sacc[0][ni], 0, 0, 0);
          sacc[1][ni] = __builtin_amdgcn_mfma_f32_16x16x32_bf16(aq[1][kd], bk, sacc[1][ni], 0, 0, 0);
        }
      }
    }

    // ---- online softmax per m-tile; P written to this wave's LDS region ----
#pragma unroll
    for (int mi = 0; mi < 2; mi++) {
      float rmax[4] = {NEG, NEG, NEG, NEG};
#pragma unroll
      for (int ni = 0; ni < 8; ni++) {
        if (ni <= nlim) {
          // mask only tiles that straddle/cross the diagonal (wave-uniform test)
          if (s0 + ni * 16 + 15 > qw0 + mi * 16) {
            const int t_base = qw0 + mi * 16 + quad * 4;
            const int s_abs = s0 + ni * 16 + l16;
#pragma unroll
            for (int r = 0; r < 4; r++)
              if (s_abs > t_base + r) sacc[mi][ni][r] = NEG;
          }
#pragma unroll
          for (int r = 0; r < 4; r++) rmax[r] = fmaxf(rmax[r], sacc[mi][ni][r]);
        }
      }
#pragma unroll
      for (int r = 0; r < 4; r++)
#pragma unroll
        for (int sh = 1; sh < 16; sh <<= 1)
          rmax[r] = fmaxf(rmax[r], __shfl_xor(rmax[r], sh));

      // deferred rescale (T13): only pay the alpha pass when max grew past threshold
      // 54 raw ~= 8 exp2-units -> p bounded by 2^8, fine in bf16/f32
      int ok = 1;
#pragma unroll
      for (int r = 0; r < 4; r++) ok &= (rmax[r] <= mrow[mi][r] + 54.0f) ? 1 : 0;
      if (!__all(ok)) {
#pragma unroll
        for (int r = 0; r < 4; r++) {
          float mnew = fmaxf(mrow[mi][r], rmax[r]);
          float alpha = EXP2((mrow[mi][r] - mnew) * cs);   // m=-inf -> alpha=0 first iter
          mrow[mi][r] = mnew;
          lrow[mi][r] *= alpha;
#pragma unroll
          for (int di = 0; di < 6; di++) acc_o[mi][di][r] *= alpha;
        }
      }

      float nmc[4];
#pragma unroll
      for (int r = 0; r < 4; r++) nmc[r] = -mrow[mi][r] * cs;
      float rsum[4] = {0.f, 0.f, 0.f, 0.f};
#pragma unroll
      for (int ni = 0; ni < 8; ni++) {
        if (ni <= nlim) {
#pragma unroll
          for (int r = 0; r < 4; r++) {
            float p = EXP2(fmaf(sacc[mi][ni][r], cs, nmc[r]));  // masked: exp2(-inf)=0
            rsum[r] += p;
            Pw[(mi * 16 + quad * 4 + r) * 136 + ni * 16 + l16] = f2bf(p);
          }
        }
      }
#pragma unroll
      for (int r = 0; r < 4; r++) lrow[mi][r] += rsum[r];   // per-lane partial; reduce at end
    }

    // ---- O += P V : P from own-wave LDS (lgkmcnt orders), V^T direct from global ----
#pragma unroll
    for (int kc = 0; kc < 4; kc++) {
      if (kc <= klim) {
        bf16x8 ap0 = *(const bf16x8*)&Pw[l16 * 136 + kc * 32 + quad * 8];
        bf16x8 ap1 = *(const bf16x8*)&Pw[(16 + l16) * 136 + kc * 32 + quad * 8];
#pragma unroll
        for (int di = 0; di < 6; di++) {
          bf16x8 bv = *(const bf16x8*)(Vt + (di * 16 + l16) * Tz + s0 + kc * 32 + quad * 8);
          acc_o[0][di] = __builtin_amdgcn_mfma_f32_16x16x32_bf16(ap0, bv, acc_o[0][di], 0, 0, 0);
          acc_o[1][di] = __builtin_amdgcn_mfma_f32_16x16x32_bf16(ap1, bv, acc_o[1][di], 0, 0, 0);
        }
      }
    }
  }

#pragma unroll
  for (int mi = 0; mi < 2; mi++) {
#pragma unroll
    for (int r = 0; r < 4; r++) {
#pragma unroll
      for (int sh = 1; sh < 16; sh <<= 1)
        lrow[mi][r] += __shfl_xor(lrow[mi][r], sh);          // deferred l reduction
      float linv = 1.f / lrow[mi][r];
      int t = qw0 + mi * 16 + quad * 4 + r;
#pragma unroll
      for (int di = 0; di < 6; di++) {
        int d = di * 16 + l16;
        y[(b * Tz + t) * Cz + h * Dz + d] = f2bf(acc_o[mi][di][r] * linv);
      }
    }
  }
}

// ---- workspace layout (bytes) ----
#define OFF_XB   0u
#define OFF_WAT  12582912u            // 8192*768*2
#define OFF_WPT  16121856u            // + 2304*768*2
#define OFF_QKV  17301504u            // + 768*768*2
#define OFF_Y    55050240u            // + 3*64*1024*96*2

extern "C" void kernel_launch(void* const* d_in, const int* in_sizes, int n_in,
                              void* d_out, int out_size, void* d_ws, size_t ws_size,
                              hipStream_t stream) {
  const float* x  = (const float*)d_in[0];
  const float* Wa = (const float*)d_in[1];
  const float* Wp = (const float*)d_in[2];
  float* out = (float*)d_out;
  uint8_t* ws = (uint8_t*)d_ws;
  unsigned short* xb  = (unsigned short*)(ws + OFF_XB);
  unsigned short* Wat = (unsigned short*)(ws + OFF_WAT);
  unsigned short* Wpt = (unsigned short*)(ws + OFF_WPT);
  unsigned short* qkv = (unsigned short*)(ws + OFF_QKV);
  unsigned short* y   = (unsigned short*)(ws + OFF_Y);

  cast_f32_bf16<<<6144, 256, 0, stream>>>(x, xb);
  transpose_cast<<<dim3(36, 12), 256, 0, stream>>>(Wa, Wat, 768, 2304);
  transpose_cast<<<dim3(12, 12), 256, 0, stream>>>(Wp, Wpt, 768, 768);
  gemm128<0><<<dim3(64, 18), 256, 0, stream>>>(xb, Wat, qkv, nullptr);
  attn<<<dim3(64, 8), 256, 0, stream>>>(qkv, y);
  gemm128<1><<<dim3(64, 6), 256, 0, stream>>>(y, Wpt, nullptr, out);
}

// Round 2
// 223.328 us; speedup vs baseline: 1.0007x; 1.0007x over previous
//
#include <hip/hip_runtime.h>
#include <stdint.h>

// ---- problem constants ----
#define Bz 8
#define Tz 1024
#define Cz 768
#define Hz 8
#define Dz 96
#define BHz 64            // Bz*Hz
#define Kz 768

typedef __bf16 bf16x8 __attribute__((ext_vector_type(8)));
typedef unsigned short u16x8 __attribute__((ext_vector_type(8)));
typedef float f32x4 __attribute__((ext_vector_type(4)));

__device__ __forceinline__ unsigned short f2bf(float f) {
  union { float f; unsigned int u; } v; v.f = f;
  unsigned int u = v.u;
  return (unsigned short)((u + 0x7fffu + ((u >> 16) & 1u)) >> 16);
}

#if defined(__has_builtin)
#if __has_builtin(__builtin_amdgcn_exp2f)
#define EXP2(x) __builtin_amdgcn_exp2f(x)
#endif
#endif
#ifndef EXP2
#define EXP2(x) __expf((x) * 0.6931471805599453f)
#endif

// async global->LDS, 16B per lane; LDS dest must be wave-uniform base (+lane*16 implicit)
typedef const __attribute__((address_space(1))) void* gas_ptr;
typedef __attribute__((address_space(3))) void* las_ptr;
__device__ __forceinline__ void gl16(const void* g, void* l) {
  __builtin_amdgcn_global_load_lds((gas_ptr)g, (las_ptr)l, 16, 0, 0);
}

// ---- cast x (fp32) -> bf16, 4 elems/thread ----
__global__ __launch_bounds__(256) void cast_f32_bf16(const float* __restrict__ in,
                                                     unsigned short* __restrict__ out) {
  int i = (blockIdx.x * 256 + threadIdx.x) * 4;
  float4 v = *(const float4*)(in + i);
  union { unsigned short s[4]; uint2 u; } o;
  o.s[0] = f2bf(v.x); o.s[1] = f2bf(v.y); o.s[2] = f2bf(v.z); o.s[3] = f2bf(v.w);
  *(uint2*)(out + i) = o.u;
}

// ---- transpose + cast: in[R][Cc] fp32 -> out[Cc][R] bf16 ----
__global__ __launch_bounds__(256) void transpose_cast(const float* __restrict__ in,
                                                      unsigned short* __restrict__ out,
                                                      int R, int Cc) {
  __shared__ unsigned short t[64][72];
  int bx = blockIdx.x * 64;   // col base of in
  int by = blockIdx.y * 64;   // row base of in
  int tid = threadIdx.x;
#pragma unroll
  for (int i = 0; i < 16; i++) {
    int idx = tid + i * 256;
    int r = idx >> 6, c = idx & 63;
    t[c][r] = f2bf(in[(by + r) * Cc + bx + c]);
  }
  __syncthreads();
#pragma unroll
  for (int i = 0; i < 16; i++) {
    int idx = tid + i * 256;
    int r = idx >> 6, c = idx & 63;
    out[(bx + r) * R + by + c] = t[r][c];
  }
}

// ---- 128x128 MFMA bf16 GEMM with global_load_lds staging (m97 structure) ----
// A[M][K] bf16, Bt[N][K] bf16
// MODE 0: epilogue scatters bf16 into qkv: Q,K as [which][64][1024][96];
//         V third written TRANSPOSED as [64][96][1024] (V^T) so attn can
//         bulk-stage it into LDS with vectorized loads.
// MODE 1: epilogue writes fp32 C[M][768]
template <int MODE>
__global__ __launch_bounds__(256)
void gemm128(const unsigned short* __restrict__ A,
             const unsigned short* __restrict__ Bt,
             unsigned short* __restrict__ obf,
             float* __restrict__ of32) {
  __shared__ unsigned short Asm[128 * 32];  // unpadded: required by global_load_lds lane order
  __shared__ unsigned short Bsm[128 * 32];
  const int tid = threadIdx.x;
  const int wave = tid >> 6, lane = tid & 63;
  const int quad = lane >> 4, l16 = lane & 15;
  const int bm = blockIdx.x, bn = blockIdx.y;
  const int wm = (wave >> 1) * 64, wn = (wave & 1) * 64;

  f32x4 zero = {0.f, 0.f, 0.f, 0.f};
  f32x4 acc[4][4];
#pragma unroll
  for (int i = 0; i < 4; i++)
#pragma unroll
    for (int j = 0; j < 4; j++) acc[i][j] = zero;

  // staging map: wave w issue q covers rows w*32+q*16 .. +15; lane l -> row +(l>>2), k-part (l&3)*8
  const int rr = lane >> 2, c8 = (lane & 3) * 8;
  const unsigned short* Ag0 = A + (size_t)(bm * 128 + wave * 32 + rr) * Kz + c8;
  const unsigned short* Ag1 = Ag0 + 16 * Kz;
  const unsigned short* Bg0 = Bt + (size_t)(bn * 128 + wave * 32 + rr) * Kz + c8;
  const unsigned short* Bg1 = Bg0 + 16 * Kz;
  unsigned short* lA0 = &Asm[wave * 1024];      // elements; bytes = wave*2048
  unsigned short* lA1 = lA0 + 512;
  unsigned short* lB0 = &Bsm[wave * 1024];
  unsigned short* lB1 = lB0 + 512;

  for (int k0 = 0; k0 < Kz; k0 += 32) {
    __syncthreads();                 // WAR: previous frag reads done
    gl16(Ag0 + k0, lA0);
    gl16(Ag1 + k0, lA1);
    gl16(Bg0 + k0, lB0);
    gl16(Bg1 + k0, lB1);
    __syncthreads();                 // drains vmcnt(0) then barrier
    bf16x8 af[4], bfr[4];
#pragma unroll
    for (int mi = 0; mi < 4; mi++)
      af[mi] = *(const bf16x8*)&Asm[(wm + mi * 16 + l16) * 32 + quad * 8];
#pragma unroll
    for (int ni = 0; ni < 4; ni++)
      bfr[ni] = *(const bf16x8*)&Bsm[(wn + ni * 16 + l16) * 32 + quad * 8];
#pragma unroll
    for (int mi = 0; mi < 4; mi++)
#pragma unroll
      for (int ni = 0; ni < 4; ni++)
        acc[mi][ni] = __builtin_amdgcn_mfma_f32_16x16x32_bf16(af[mi], bfr[ni], acc[mi][ni], 0, 0, 0);
  }

#pragma unroll
  for (int mi = 0; mi < 4; mi++) {
    int row = bm * 128 + wm + mi * 16 + quad * 4;
    if (MODE == 0) {
      int b = row >> 10;
      int t = row & 1023;
#pragma unroll
      for (int ni = 0; ni < 4; ni++) {
        int col = bn * 128 + wn + ni * 16 + l16;
        int which = col / 768;        // wave-uniform per fragment (16 | 768)
        int cc = col - which * 768;
        int h = cc / 96;
        int d = cc - h * 96;
        if (which == 2) {
          // V^T layout: [bh][d][t]; r increments t -> 4 contiguous bf16 = one 8B store
          int base = ((2 * 64 + b * 8 + h) * 96 + d) * 1024 + t;
          union { unsigned short s[4]; uint2 u; } o;
#pragma unroll
          for (int r = 0; r < 4; r++) o.s[r] = f2bf(acc[mi][ni][r]);
          *(uint2*)(obf + base) = o.u;
        } else {
          int base = ((which * 64 + b * 8 + h) * 1024 + t) * 96 + d;
#pragma unroll
          for (int r = 0; r < 4; r++) obf[base + r * 96] = f2bf(acc[mi][ni][r]);
        }
      }
    } else {
#pragma unroll
      for (int ni = 0; ni < 4; ni++) {
        int col = bn * 128 + wn + ni * 16 + l16;
#pragma unroll
        for (int r = 0; r < 4; r++) of32[(row + r) * 768 + col] = acc[mi][ni][r];
      }
    }
  }
}

// ---- flash attention v2: 1 block = (b,h) x 128 q-rows; 4 waves x 32 rows; BS=128 ----
// V staged in LDS (shared by 4 waves) via T14 async split: global->reg loads issued
// before QK^T (latency hidden under compute), reg->LDS writes after the WAR barrier.
// Psm/Vsm use a 16B-chunk XOR swizzle (chunk ^= row&7) to kill the 8-way b128 conflicts.
__global__ __launch_bounds__(256, 2)
void attn(const unsigned short* __restrict__ qkv, unsigned short* __restrict__ y) {
  const int bh = blockIdx.x;
  const int by = blockIdx.y;
  // balanced pairing: CU holding blocks n and n+256 gets tiles summing to 9 iters
  const int q0 = ((by < 4) ? (7 - by) : (by - 4)) * 128;
  const int tid = threadIdx.x;
  const int wave = tid >> 6, lane = tid & 63;
  const int quad = lane >> 4, l16 = lane & 15;
  const int qw0 = q0 + wave * 32;          // this wave's 32 q-rows (2 m-tiles)
  const int b = bh >> 3, h = bh & 7;

  const unsigned short* Qh = qkv + bh * Tz * Dz;
  const unsigned short* Kh = qkv + (BHz + bh) * Tz * Dz;
  const unsigned short* Vt = qkv + 2 * BHz * Tz * Dz + bh * Dz * Tz;  // [d][t]

  __shared__ unsigned short Vsm[96 * 136];       // V^T [d][s], stride 136, chunk-swizzled
  __shared__ unsigned short Psm[4 * 32 * 136];   // per-wave P [32 q][128 s], chunk-swizzled
  unsigned short* Pw = Psm + wave * 32 * 136;

  // V staging thread map: round g covers rows g*16 + (tid>>4), chunk tid&15 (8 elems)
  const int vd = tid >> 4;                 // d within 16-row group
  const int vc = tid & 15;                 // 16B chunk within 128-col row
  const int vsw = ((vc ^ (vd & 7)) << 3);  // swizzled element offset within row

  bf16x8 aq[2][3];
#pragma unroll
  for (int mi = 0; mi < 2; mi++)
#pragma unroll
    for (int kd = 0; kd < 3; kd++)
      aq[mi][kd] = *(const bf16x8*)(Qh + (qw0 + mi * 16 + l16) * Dz + kd * 32 + quad * 8);

  f32x4 zero = {0.f, 0.f, 0.f, 0.f};
  f32x4 acc_o[2][6];
#pragma unroll
  for (int mi = 0; mi < 2; mi++)
#pragma unroll
    for (int i = 0; i < 6; i++) acc_o[mi][i] = zero;
  const float NEG = -__builtin_inff();
  float mrow[2][4], lrow[2][4];              // mrow raw-score domain; lrow per-LANE partial
#pragma unroll
  for (int mi = 0; mi < 2; mi++)
#pragma unroll
    for (int r = 0; r < 4; r++) { mrow[mi][r] = NEG; lrow[mi][r] = 0.f; }
  const float cs = 0.14724538519872735f;    // (1/sqrt(96)) * log2(e): exp2-domain softmax

  for (int s0 = 0; s0 <= q0; s0 += 128) {
    // ---- T14 issue-early: V^T tile global->reg; latency hides under QK^T+softmax ----
    u16x8 vreg[6];
#pragma unroll
    for (int g = 0; g < 6; g++)
      vreg[g] = *(const u16x8*)(Vt + (g * 16 + vd) * Tz + s0 + vc * 8);

    const int srem = qw0 + 31 - s0;              // >= 31 always; srem%32==31
    const int nlim = min(7, srem >> 4);          // last 16-wide s tile with unmasked cols
    const int klim = min(3, srem >> 5);          // last 32-wide PV k chunk

    // ---- S = Q K^T (both m-tiles share K fragments) ----
    f32x4 sacc[2][8];
#pragma unroll
    for (int ni = 0; ni < 8; ni++) {
      if (ni <= nlim) {
        sacc[0][ni] = zero; sacc[1][ni] = zero;
#pragma unroll
        for (int kd = 0; kd < 3; kd++) {
          bf16x8 bk = *(const bf16x8*)(Kh + (s0 + ni * 16 + l16) * Dz + kd * 32 + quad * 8);
          sacc[0][ni] = __builtin_amdgcn_mfma_f32_16x16x32_bf16(aq[0][kd], bk, sacc[0][ni], 0, 0, 0);
          sacc[1][ni] = __builtin_amdgcn_mfma_f32_16x16x32_bf16(aq[1][kd], bk, sacc[1][ni], 0, 0, 0);
        }
      }
    }

    // ---- online softmax per m-tile; P written to this wave's LDS region ----
#pragma unroll
    for (int mi = 0; mi < 2; mi++) {
      float rmax[4] = {NEG, NEG, NEG, NEG};
#pragma unroll
      for (int ni = 0; ni < 8; ni++) {
        if (ni <= nlim) {
          // mask only tiles that straddle/cross the diagonal (wave-uniform test)
          if (s0 + ni * 16 + 15 > qw0 + mi * 16) {
            const int t_base = qw0 + mi * 16 + quad * 4;
            const int s_abs = s0 + ni * 16 + l16;
#pragma unroll
            for (int r = 0; r < 4; r++)
              if (s_abs > t_base + r) sacc[mi][ni][r] = NEG;
          }
#pragma unroll
          for (int r = 0; r < 4; r++) rmax[r] = fmaxf(rmax[r], sacc[mi][ni][r]);
        }
      }
#pragma unroll
      for (int r = 0; r < 4; r++)
#pragma unroll
        for (int sh = 1; sh < 16; sh <<= 1)
          rmax[r] = fmaxf(rmax[r], __shfl_xor(rmax[r], sh));

      // deferred rescale (T13): only pay the alpha pass when max grew past threshold
      // 54 raw ~= 8 exp2-units -> p bounded by 2^8, fine in bf16/f32
      int ok = 1;
#pragma unroll
      for (int r = 0; r < 4; r++) ok &= (rmax[r] <= mrow[mi][r] + 54.0f) ? 1 : 0;
      if (!__all(ok)) {
#pragma unroll
        for (int r = 0; r < 4; r++) {
          float mnew = fmaxf(mrow[mi][r], rmax[r]);
          float alpha = EXP2((mrow[mi][r] - mnew) * cs);   // m=-inf -> alpha=0 first iter
          mrow[mi][r] = mnew;
          lrow[mi][r] *= alpha;
#pragma unroll
          for (int di = 0; di < 6; di++) acc_o[mi][di][r] *= alpha;
        }
      }

      float nmc[4];
#pragma unroll
      for (int r = 0; r < 4; r++) nmc[r] = -mrow[mi][r] * cs;
      float rsum[4] = {0.f, 0.f, 0.f, 0.f};
#pragma unroll
      for (int ni = 0; ni < 8; ni++) {
        if (ni <= nlim) {
          const int pchunk = ni * 2 + (l16 >> 3);          // 16B chunk of col ni*16+l16
          const int psub = l16 & 7;
#pragma unroll
          for (int r = 0; r < 4; r++) {
            float p = EXP2(fmaf(sacc[mi][ni][r], cs, nmc[r]));  // masked: exp2(-inf)=0
            rsum[r] += p;
            int row = mi * 16 + quad * 4 + r;
            Pw[row * 136 + ((pchunk ^ (row & 7)) << 3) + psub] = f2bf(p);
          }
        }
      }
#pragma unroll
      for (int r = 0; r < 4; r++) lrow[mi][r] += rsum[r];   // per-lane partial; reduce at end
    }

    // ---- T14 write-late: V regs -> LDS after WAR barrier ----
    __syncthreads();                 // prior iter's Vsm reads done
#pragma unroll
    for (int g = 0; g < 6; g++)
      *(u16x8*)&Vsm[(g * 16 + vd) * 136 + vsw] = vreg[g];
    __syncthreads();                 // Vsm ready

    // ---- O += P V : P from own-wave LDS (lgkmcnt orders), V from swizzled Vsm ----
#pragma unroll
    for (int kc = 0; kc < 4; kc++) {
      if (kc <= klim) {
        const int rsw = (((kc * 4 + quad) ^ (l16 & 7)) << 3);  // read swizzle (row&7 == l16&7)
        bf16x8 ap0 = *(const bf16x8*)&Pw[l16 * 136 + rsw];
        bf16x8 ap1 = *(const bf16x8*)&Pw[(16 + l16) * 136 + rsw];
#pragma unroll
        for (int di = 0; di < 6; di++) {
          bf16x8 bv = *(const bf16x8*)&Vsm[(di * 16 + l16) * 136 + rsw];
          acc_o[0][di] = __builtin_amdgcn_mfma_f32_16x16x32_bf16(ap0, bv, acc_o[0][di], 0, 0, 0);
          acc_o[1][di] = __builtin_amdgcn_mfma_f32_16x16x32_bf16(ap1, bv, acc_o[1][di], 0, 0, 0);
        }
      }
    }
  }

#pragma unroll
  for (int mi = 0; mi < 2; mi++) {
#pragma unroll
    for (int r = 0; r < 4; r++) {
#pragma unroll
      for (int sh = 1; sh < 16; sh <<= 1)
        lrow[mi][r] += __shfl_xor(lrow[mi][r], sh);          // deferred l reduction
      float linv = 1.f / lrow[mi][r];
      int t = qw0 + mi * 16 + quad * 4 + r;
#pragma unroll
      for (int di = 0; di < 6; di++) {
        int d = di * 16 + l16;
        y[(b * Tz + t) * Cz + h * Dz + d] = f2bf(acc_o[mi][di][r] * linv);
      }
    }
  }
}

// ---- workspace layout (bytes) ----
#define OFF_XB   0u
#define OFF_WAT  12582912u            // 8192*768*2
#define OFF_WPT  16121856u            // + 2304*768*2
#define OFF_QKV  17301504u            // + 768*768*2
#define OFF_Y    55050240u            // + 3*64*1024*96*2

extern "C" void kernel_launch(void* const* d_in, const int* in_sizes, int n_in,
                              void* d_out, int out_size, void* d_ws, size_t ws_size,
                              hipStream_t stream) {
  const float* x  = (const float*)d_in[0];
  const float* Wa = (const float*)d_in[1];
  const float* Wp = (const float*)d_in[2];
  float* out = (float*)d_out;
  uint8_t* ws = (uint8_t*)d_ws;
  unsigned short* xb  = (unsigned short*)(ws + OFF_XB);
  unsigned short* Wat = (unsigned short*)(ws + OFF_WAT);
  unsigned short* Wpt = (unsigned short*)(ws + OFF_WPT);
  unsigned short* qkv = (unsigned short*)(ws + OFF_QKV);
  unsigned short* y   = (unsigned short*)(ws + OFF_Y);

  cast_f32_bf16<<<6144, 256, 0, stream>>>(x, xb);
  transpose_cast<<<dim3(36, 12), 256, 0, stream>>>(Wa, Wat, 768, 2304);
  transpose_cast<<<dim3(12, 12), 256, 0, stream>>>(Wp, Wpt, 768, 768);
  gemm128<0><<<dim3(64, 18), 256, 0, stream>>>(xb, Wat, qkv, nullptr);
  attn<<<dim3(64, 8), 256, 0, stream>>>(qkv, y);
  gemm128<1><<<dim3(64, 6), 256, 0, stream>>>(y, Wpt, nullptr, out);
}

// Round 3
// 210.337 us; speedup vs baseline: 1.0625x; 1.0618x over previous
//
#include <hip/hip_runtime.h>
#include <stdint.h>

// ---- problem constants ----
#define Bz 8
#define Tz 1024
#define Cz 768
#define Hz 8
#define Dz 96
#define BHz 64            // Bz*Hz
#define Kz 768

typedef __bf16 bf16x8 __attribute__((ext_vector_type(8)));
typedef unsigned short u16x8 __attribute__((ext_vector_type(8)));
typedef float f32x4 __attribute__((ext_vector_type(4)));

__device__ __forceinline__ unsigned short f2bf(float f) {
  union { float f; unsigned int u; } v; v.f = f;
  unsigned int u = v.u;
  return (unsigned short)((u + 0x7fffu + ((u >> 16) & 1u)) >> 16);
}

#if defined(__has_builtin)
#if __has_builtin(__builtin_amdgcn_exp2f)
#define EXP2(x) __builtin_amdgcn_exp2f(x)
#endif
#endif
#ifndef EXP2
#define EXP2(x) __expf((x) * 0.6931471805599453f)
#endif

// async global->LDS, 16B per lane; LDS dest must be wave-uniform base (+lane*16 implicit)
typedef const __attribute__((address_space(1))) void* gas_ptr;
typedef __attribute__((address_space(3))) void* las_ptr;
__device__ __forceinline__ void gl16(const void* g, void* l) {
  __builtin_amdgcn_global_load_lds((gas_ptr)g, (las_ptr)l, 16, 0, 0);
}

// ---- cast x (fp32) -> bf16, 4 elems/thread ----
__global__ __launch_bounds__(256) void cast_f32_bf16(const float* __restrict__ in,
                                                     unsigned short* __restrict__ out) {
  int i = (blockIdx.x * 256 + threadIdx.x) * 4;
  float4 v = *(const float4*)(in + i);
  union { unsigned short s[4]; uint2 u; } o;
  o.s[0] = f2bf(v.x); o.s[1] = f2bf(v.y); o.s[2] = f2bf(v.z); o.s[3] = f2bf(v.w);
  *(uint2*)(out + i) = o.u;
}

// ---- transpose + cast: in[R][Cc] fp32 -> out[Cc][R] bf16 ----
__global__ __launch_bounds__(256) void transpose_cast(const float* __restrict__ in,
                                                      unsigned short* __restrict__ out,
                                                      int R, int Cc) {
  __shared__ unsigned short t[64][72];
  int bx = blockIdx.x * 64;   // col base of in
  int by = blockIdx.y * 64;   // row base of in
  int tid = threadIdx.x;
#pragma unroll
  for (int i = 0; i < 16; i++) {
    int idx = tid + i * 256;
    int r = idx >> 6, c = idx & 63;
    t[c][r] = f2bf(in[(by + r) * Cc + bx + c]);
  }
  __syncthreads();
#pragma unroll
  for (int i = 0; i < 16; i++) {
    int idx = tid + i * 256;
    int r = idx >> 6, c = idx & 63;
    out[(bx + r) * R + by + c] = t[r][c];
  }
}

// ---- 128x128 MFMA bf16 GEMM with global_load_lds staging (m97 structure) ----
// A[M][K] bf16, Bt[N][K] bf16
// MODE 0: epilogue scatters bf16 into qkv: Q,K as [which][64][1024][96];
//         V third written TRANSPOSED as [64][96][1024] (V^T) so attn can
//         bulk-stage it into LDS with vectorized b128 copies (no transpose).
// MODE 1: epilogue writes fp32 C[M][768]
template <int MODE>
__global__ __launch_bounds__(256)
void gemm128(const unsigned short* __restrict__ A,
             const unsigned short* __restrict__ Bt,
             unsigned short* __restrict__ obf,
             float* __restrict__ of32) {
  __shared__ unsigned short Asm[128 * 32];  // unpadded: required by global_load_lds lane order
  __shared__ unsigned short Bsm[128 * 32];
  const int tid = threadIdx.x;
  const int wave = tid >> 6, lane = tid & 63;
  const int quad = lane >> 4, l16 = lane & 15;
  const int bm = blockIdx.x, bn = blockIdx.y;
  const int wm = (wave >> 1) * 64, wn = (wave & 1) * 64;

  f32x4 zero = {0.f, 0.f, 0.f, 0.f};
  f32x4 acc[4][4];
#pragma unroll
  for (int i = 0; i < 4; i++)
#pragma unroll
    for (int j = 0; j < 4; j++) acc[i][j] = zero;

  // staging map: wave w issue q covers rows w*32+q*16 .. +15; lane l -> row +(l>>2), k-part (l&3)*8
  const int rr = lane >> 2, c8 = (lane & 3) * 8;
  const unsigned short* Ag0 = A + (size_t)(bm * 128 + wave * 32 + rr) * Kz + c8;
  const unsigned short* Ag1 = Ag0 + 16 * Kz;
  const unsigned short* Bg0 = Bt + (size_t)(bn * 128 + wave * 32 + rr) * Kz + c8;
  const unsigned short* Bg1 = Bg0 + 16 * Kz;
  unsigned short* lA0 = &Asm[wave * 1024];      // elements; bytes = wave*2048
  unsigned short* lA1 = lA0 + 512;
  unsigned short* lB0 = &Bsm[wave * 1024];
  unsigned short* lB1 = lB0 + 512;

  for (int k0 = 0; k0 < Kz; k0 += 32) {
    __syncthreads();                 // WAR: previous frag reads done
    gl16(Ag0 + k0, lA0);
    gl16(Ag1 + k0, lA1);
    gl16(Bg0 + k0, lB0);
    gl16(Bg1 + k0, lB1);
    __syncthreads();                 // drains vmcnt(0) then barrier
    bf16x8 af[4], bfr[4];
#pragma unroll
    for (int mi = 0; mi < 4; mi++)
      af[mi] = *(const bf16x8*)&Asm[(wm + mi * 16 + l16) * 32 + quad * 8];
#pragma unroll
    for (int ni = 0; ni < 4; ni++)
      bfr[ni] = *(const bf16x8*)&Bsm[(wn + ni * 16 + l16) * 32 + quad * 8];
#pragma unroll
    for (int mi = 0; mi < 4; mi++)
#pragma unroll
      for (int ni = 0; ni < 4; ni++)
        acc[mi][ni] = __builtin_amdgcn_mfma_f32_16x16x32_bf16(af[mi], bfr[ni], acc[mi][ni], 0, 0, 0);
  }

#pragma unroll
  for (int mi = 0; mi < 4; mi++) {
    int row = bm * 128 + wm + mi * 16 + quad * 4;
    if (MODE == 0) {
      int b = row >> 10;
      int t = row & 1023;
#pragma unroll
      for (int ni = 0; ni < 4; ni++) {
        int col = bn * 128 + wn + ni * 16 + l16;
        int which = col / 768;        // wave-uniform per fragment (16 | 768)
        int cc = col - which * 768;
        int h = cc / 96;
        int d = cc - h * 96;
        if (which == 2) {
          // V^T layout: [bh][d][t]; r increments t -> 4 contiguous bf16 = one 8B store
          int base = ((2 * 64 + b * 8 + h) * 96 + d) * 1024 + t;
          union { unsigned short s[4]; uint2 u; } o;
#pragma unroll
          for (int r = 0; r < 4; r++) o.s[r] = f2bf(acc[mi][ni][r]);
          *(uint2*)(obf + base) = o.u;
        } else {
          int base = ((which * 64 + b * 8 + h) * 1024 + t) * 96 + d;
#pragma unroll
          for (int r = 0; r < 4; r++) obf[base + r * 96] = f2bf(acc[mi][ni][r]);
        }
      }
    } else {
#pragma unroll
      for (int ni = 0; ni < 4; ni++) {
        int col = bn * 128 + wn + ni * 16 + l16;
#pragma unroll
        for (int r = 0; r < 4; r++) of32[(row + r) * 768 + col] = acc[mi][ni][r];
      }
    }
  }
}

// ---- flash attention v2: 1 block = (b,h) x 128 q-rows; 4 waves x 32 rows; BS=128 ----
// Round-3 consolidation: round-0 LDS addressing (stride 136, NO swizzle — 272B row
// stride = 4-bank offset tiles b128 reads conflict-free), balanced q-tile pairing,
// V^T bulk staging with T14 issue-early/write-late split, exp2-domain softmax diet.
__global__ __launch_bounds__(256, 2)
void attn(const unsigned short* __restrict__ qkv, unsigned short* __restrict__ y) {
  const int bh = blockIdx.x;
  const int by = blockIdx.y;
  // balanced pairing: CU holding blocks n and n+256 gets tiles summing to 9 iters
  const int q0 = ((by < 4) ? (7 - by) : (by - 4)) * 128;
  const int tid = threadIdx.x;
  const int wave = tid >> 6, lane = tid & 63;
  const int quad = lane >> 4, l16 = lane & 15;
  const int qw0 = q0 + wave * 32;          // this wave's 32 q-rows (2 m-tiles)
  const int b = bh >> 3, h = bh & 7;

  const unsigned short* Qh = qkv + bh * Tz * Dz;
  const unsigned short* Kh = qkv + (BHz + bh) * Tz * Dz;
  const unsigned short* Vt = qkv + 2 * BHz * Tz * Dz + bh * Dz * Tz;  // V^T [d][t]

  __shared__ unsigned short Vsm[96 * 136];       // V^T [d][s], stride 136
  __shared__ unsigned short Psm[4 * 32 * 136];   // per-wave P [32 q][128 s]
  unsigned short* Pw = Psm + wave * 32 * 136;

  // V staging thread map: round g covers rows g*16 + (tid>>4), 16B chunk tid&15
  const int vd = tid >> 4;                 // d within 16-row group
  const int vc = tid & 15;                 // 16B chunk within 128-col row

  bf16x8 aq[2][3];
#pragma unroll
  for (int mi = 0; mi < 2; mi++)
#pragma unroll
    for (int kd = 0; kd < 3; kd++)
      aq[mi][kd] = *(const bf16x8*)(Qh + (qw0 + mi * 16 + l16) * Dz + kd * 32 + quad * 8);

  f32x4 zero = {0.f, 0.f, 0.f, 0.f};
  f32x4 acc_o[2][6];
#pragma unroll
  for (int mi = 0; mi < 2; mi++)
#pragma unroll
    for (int i = 0; i < 6; i++) acc_o[mi][i] = zero;
  const float NEG = -__builtin_inff();
  float mrow[2][4], lrow[2][4];              // mrow raw-score domain; lrow per-LANE partial
#pragma unroll
  for (int mi = 0; mi < 2; mi++)
#pragma unroll
    for (int r = 0; r < 4; r++) { mrow[mi][r] = NEG; lrow[mi][r] = 0.f; }
  const float cs = 0.14724538519872735f;    // (1/sqrt(96)) * log2(e): exp2-domain softmax

  for (int s0 = 0; s0 <= q0; s0 += 128) {
    // ---- T14 issue-early: V^T tile global->reg; latency hides under QK^T+softmax ----
    u16x8 vreg[6];
#pragma unroll
    for (int g = 0; g < 6; g++)
      vreg[g] = *(const u16x8*)(Vt + (g * 16 + vd) * Tz + s0 + vc * 8);

    const int srem = qw0 + 31 - s0;              // >= 31 always; srem%32==31
    const int nlim = min(7, srem >> 4);          // last 16-wide s tile with unmasked cols
    const int klim = min(3, srem >> 5);          // last 32-wide PV k chunk

    // ---- S = Q K^T (both m-tiles share K fragments) ----
    f32x4 sacc[2][8];
#pragma unroll
    for (int ni = 0; ni < 8; ni++) {
      if (ni <= nlim) {
        sacc[0][ni] = zero; sacc[1][ni] = zero;
#pragma unroll
        for (int kd = 0; kd < 3; kd++) {
          bf16x8 bk = *(const bf16x8*)(Kh + (s0 + ni * 16 + l16) * Dz + kd * 32 + quad * 8);
          sacc[0][ni] = __builtin_amdgcn_mfma_f32_16x16x32_bf16(aq[0][kd], bk, sacc[0][ni], 0, 0, 0);
          sacc[1][ni] = __builtin_amdgcn_mfma_f32_16x16x32_bf16(aq[1][kd], bk, sacc[1][ni], 0, 0, 0);
        }
      }
    }

    // ---- online softmax per m-tile; P written to this wave's LDS region ----
#pragma unroll
    for (int mi = 0; mi < 2; mi++) {
      float rmax[4] = {NEG, NEG, NEG, NEG};
#pragma unroll
      for (int ni = 0; ni < 8; ni++) {
        if (ni <= nlim) {
          // mask only tiles that straddle/cross the diagonal (wave-uniform test)
          if (s0 + ni * 16 + 15 > qw0 + mi * 16) {
            const int t_base = qw0 + mi * 16 + quad * 4;
            const int s_abs = s0 + ni * 16 + l16;
#pragma unroll
            for (int r = 0; r < 4; r++)
              if (s_abs > t_base + r) sacc[mi][ni][r] = NEG;
          }
#pragma unroll
          for (int r = 0; r < 4; r++) rmax[r] = fmaxf(rmax[r], sacc[mi][ni][r]);
        }
      }
#pragma unroll
      for (int r = 0; r < 4; r++)
#pragma unroll
        for (int sh = 1; sh < 16; sh <<= 1)
          rmax[r] = fmaxf(rmax[r], __shfl_xor(rmax[r], sh));

      // deferred rescale (T13): only pay the alpha pass when max grew past threshold
      // 54 raw ~= 8 exp2-units -> p bounded by 2^8, fine in bf16/f32
      int ok = 1;
#pragma unroll
      for (int r = 0; r < 4; r++) ok &= (rmax[r] <= mrow[mi][r] + 54.0f) ? 1 : 0;
      if (!__all(ok)) {
#pragma unroll
        for (int r = 0; r < 4; r++) {
          float mnew = fmaxf(mrow[mi][r], rmax[r]);
          float alpha = EXP2((mrow[mi][r] - mnew) * cs);   // m=-inf -> alpha=0 first iter
          mrow[mi][r] = mnew;
          lrow[mi][r] *= alpha;
#pragma unroll
          for (int di = 0; di < 6; di++) acc_o[mi][di][r] *= alpha;
        }
      }

      float nmc[4];
#pragma unroll
      for (int r = 0; r < 4; r++) nmc[r] = -mrow[mi][r] * cs;
      float rsum[4] = {0.f, 0.f, 0.f, 0.f};
#pragma unroll
      for (int ni = 0; ni < 8; ni++) {
        if (ni <= nlim) {
#pragma unroll
          for (int r = 0; r < 4; r++) {
            float p = EXP2(fmaf(sacc[mi][ni][r], cs, nmc[r]));  // masked: exp2(-inf)=0
            rsum[r] += p;
            Pw[(mi * 16 + quad * 4 + r) * 136 + ni * 16 + l16] = f2bf(p);
          }
        }
      }
#pragma unroll
      for (int r = 0; r < 4; r++) lrow[mi][r] += rsum[r];   // per-lane partial; reduce at end
    }

    // ---- T14 write-late: V regs -> LDS after WAR barrier (vectorized b128) ----
    __syncthreads();                 // prior iter's Vsm reads done
#pragma unroll
    for (int g = 0; g < 6; g++)
      *(u16x8*)&Vsm[(g * 16 + vd) * 136 + vc * 8] = vreg[g];
    __syncthreads();                 // Vsm ready

    // ---- O += P V : P from own-wave LDS (lgkmcnt orders), V from Vsm ----
#pragma unroll
    for (int kc = 0; kc < 4; kc++) {
      if (kc <= klim) {
        bf16x8 ap0 = *(const bf16x8*)&Pw[l16 * 136 + kc * 32 + quad * 8];
        bf16x8 ap1 = *(const bf16x8*)&Pw[(16 + l16) * 136 + kc * 32 + quad * 8];
#pragma unroll
        for (int di = 0; di < 6; di++) {
          bf16x8 bv = *(const bf16x8*)&Vsm[(di * 16 + l16) * 136 + kc * 32 + quad * 8];
          acc_o[0][di] = __builtin_amdgcn_mfma_f32_16x16x32_bf16(ap0, bv, acc_o[0][di], 0, 0, 0);
          acc_o[1][di] = __builtin_amdgcn_mfma_f32_16x16x32_bf16(ap1, bv, acc_o[1][di], 0, 0, 0);
        }
      }
    }
  }

#pragma unroll
  for (int mi = 0; mi < 2; mi++) {
#pragma unroll
    for (int r = 0; r < 4; r++) {
#pragma unroll
      for (int sh = 1; sh < 16; sh <<= 1)
        lrow[mi][r] += __shfl_xor(lrow[mi][r], sh);          // deferred l reduction
      float linv = 1.f / lrow[mi][r];
      int t = qw0 + mi * 16 + quad * 4 + r;
#pragma unroll
      for (int di = 0; di < 6; di++) {
        int d = di * 16 + l16;
        y[(b * Tz + t) * Cz + h * Dz + d] = f2bf(acc_o[mi][di][r] * linv);
      }
    }
  }
}

// ---- workspace layout (bytes) ----
#define OFF_XB   0u
#define OFF_WAT  12582912u            // 8192*768*2
#define OFF_WPT  16121856u            // + 2304*768*2
#define OFF_QKV  17301504u            // + 768*768*2
#define OFF_Y    55050240u            // + 3*64*1024*96*2

extern "C" void kernel_launch(void* const* d_in, const int* in_sizes, int n_in,
                              void* d_out, int out_size, void* d_ws, size_t ws_size,
                              hipStream_t stream) {
  const float* x  = (const float*)d_in[0];
  const float* Wa = (const float*)d_in[1];
  const float* Wp = (const float*)d_in[2];
  float* out = (float*)d_out;
  uint8_t* ws = (uint8_t*)d_ws;
  unsigned short* xb  = (unsigned short*)(ws + OFF_XB);
  unsigned short* Wat = (unsigned short*)(ws + OFF_WAT);
  unsigned short* Wpt = (unsigned short*)(ws + OFF_WPT);
  unsigned short* qkv = (unsigned short*)(ws + OFF_QKV);
  unsigned short* y   = (unsigned short*)(ws + OFF_Y);

  cast_f32_bf16<<<6144, 256, 0, stream>>>(x, xb);
  transpose_cast<<<dim3(36, 12), 256, 0, stream>>>(Wa, Wat, 768, 2304);
  transpose_cast<<<dim3(12, 12), 256, 0, stream>>>(Wp, Wpt, 768, 768);
  gemm128<0><<<dim3(64, 18), 256, 0, stream>>>(xb, Wat, qkv, nullptr);
  attn<<<dim3(64, 8), 256, 0, stream>>>(qkv, y);
  gemm128<1><<<dim3(64, 6), 256, 0, stream>>>(y, Wpt, nullptr, out);
}